// Round 9
// baseline (962.432 us; speedup 1.0000x reference)
//
#include <hip/hip_runtime.h>

// PoissonPinn, round-12: R11 base + (a) anti-phase seeding, (b) b64 LDS paths.
//
// R11 accounting: MFMA busy = 448us (= exact floor), VALU ~110us, ~390us waits
// from lockstep phase exclusion (both resident blocks synchronized) + b128
// bank pressure (3.78e7 conflict cycles, inherent to wave64 b128 here).
//
//  * One-time random stagger (blockIdx<2048, hash-scaled s_sleep, 0-26k cyc):
//    co-resident blocks de-phase permanently (block churn preserves offsets)
//    -> one block's GEMM overlaps the other's epilogue/transition.
//  * SKE 264->260 (520B rows, odd multiple of 8B): loadB/storeP become u32x2
//    (b64) pairs — 8B row alignment legally blocks b128 re-fusion; bank-pair
//    map (m + 2q + h) mod 16 is all-distinct per 16-lane group (R5's measured-
//    zero pattern). Slot-contiguous layout kept (no shuffles).
//  * Everything else identical to R11 (truncation pack2, fused boundary,
//    own-chunk register-direct mfma36, (256,2)).

constexpr int HID   = 256;
constexpr int MPTS  = 16;
constexpr int SKE   = 260;             // row stride elems (520 B, odd x 8B)
constexpr int WELEM = 3 * HID * HID;
constexpr int HLSB  = 6 * MPTS * SKE * 2;   // 49920 B

typedef __bf16 bf16x8 __attribute__((ext_vector_type(8)));
typedef float  f32x4  __attribute__((ext_vector_type(4)));
typedef unsigned int u32x4 __attribute__((ext_vector_type(4)));
typedef unsigned int u32x2 __attribute__((ext_vector_type(2)));

__device__ __forceinline__ float fast_tanh(float x) {
    float e = __expf(2.0f * x);
    return 1.0f - 2.0f / (e + 1.0f);
}

struct packed2 { unsigned hi, lo; };

__device__ __forceinline__ packed2 pack2(float x, float y) {
    const unsigned xb = __float_as_uint(x), yb = __float_as_uint(y);
    const unsigned xh = xb & 0xFFFF0000u, yh = yb & 0xFFFF0000u;
    packed2 r;
    r.hi = (xb >> 16) | yh;
    const float dx = x - __uint_as_float(xh);
    const float dy = y - __uint_as_float(yh);
    r.lo = (__float_as_uint(dx) >> 16) | (__float_as_uint(dy) & 0xFFFF0000u);
    return r;
}

__global__ void prep_w(const float* __restrict__ W1,
                       const float* __restrict__ W2,
                       const float* __restrict__ W3,
                       __bf16* __restrict__ Wh, __bf16* __restrict__ Wl) {
    const int idx = blockIdx.x * 256 + threadIdx.x;
    const int l   = idx >> 16;
    const int r   = idx & 0xFFFF;
    const int NT  = r >> 12;
    const int ks  = (r >> 9) & 7;
    const int ln  = (r >> 3) & 63;
    const int j   = r & 7;
    const int q   = ln >> 4;
    const int mm  = ln & 15;
    const int k   = ks * 32 + ((j >> 2) << 4) + q * 4 + (j & 3);
    const int n   = NT * 16 + mm;
    const float* W = (l == 0) ? W1 : (l == 1) ? W2 : W3;
    const float w  = W[k * HID + n];
    const __bf16 hi = (__bf16)w;
    Wh[idx] = hi;
    Wl[idx] = (__bf16)(w - (float)hi);
}

__global__ __launch_bounds__(256, 2)
void pinn_fused(const float* __restrict__ xe, const float* __restrict__ xb,
                const float* __restrict__ W0, const float* __restrict__ b0,
                const float* __restrict__ b1, const float* __restrict__ b2,
                const float* __restrict__ b3, const float* __restrict__ W4,
                const float* __restrict__ b4,
                const float* __restrict__ W1f, const float* __restrict__ W2f,
                const float* __restrict__ W3f,
                const __bf16* __restrict__ Wh, const __bf16* __restrict__ Wl,
                float* __restrict__ out, int neqb, int n_eq)
{
    __shared__ __align__(16) unsigned char smem[HLSB];

    const int tid  = threadIdx.x;
    const int lane = tid & 63;
    const int wv   = tid >> 6;

    if ((int)blockIdx.x >= neqb) {
        // ================= boundary path =================
        float (*HV)[HID] = (float (*)[HID])smem;
        const int rbase = wv * 4;
        const int pbase = ((int)blockIdx.x - neqb) * 16 + rbase;
        float* bout = out + n_eq;

        #pragma unroll
        for (int c = 0; c < 4; ++c) {
            const int   j  = lane + 64 * c;
            const float w  = W0[j];
            const float bb = b0[j];
            #pragma unroll
            for (int p = 0; p < 4; ++p)
                HV[rbase + p][j] = fast_tanh(xb[pbase + p] * w + bb);
        }
        __syncthreads();

        const float* Ws[3] = {W1f, W2f, W3f};
        const float* bs[3] = {b1, b2, b3};

        #pragma unroll
        for (int l = 0; l < 3; ++l) {
            const float* __restrict__ W = Ws[l];
            const float* __restrict__ b = bs[l];

            float zv[4][4];
            #pragma unroll
            for (int p = 0; p < 4; ++p)
                #pragma unroll
                for (int c = 0; c < 4; ++c)
                    zv[p][c] = b[lane + 64 * c];

            for (int i = 0; i < HID; i += 4) {
                float w[4][4];
                #pragma unroll
                for (int qq = 0; qq < 4; ++qq)
                    #pragma unroll
                    for (int c = 0; c < 4; ++c)
                        w[qq][c] = W[(i + qq) * HID + lane + 64 * c];

                #pragma unroll
                for (int p = 0; p < 4; ++p) {
                    const float4 av = *(const float4*)&HV[rbase + p][i];
                    #pragma unroll
                    for (int qq = 0; qq < 4; ++qq) {
                        const float a_v = ((const float*)&av)[qq];
                        #pragma unroll
                        for (int c = 0; c < 4; ++c)
                            zv[p][c] = fmaf(a_v, w[qq][c], zv[p][c]);
                    }
                }
            }
            __syncthreads();

            #pragma unroll
            for (int p = 0; p < 4; ++p)
                #pragma unroll
                for (int c = 0; c < 4; ++c)
                    HV[rbase + p][lane + 64 * c] = fast_tanh(zv[p][c]);
            __syncthreads();
        }

        const float bias4 = b4[0];
        #pragma unroll
        for (int p = 0; p < 4; ++p) {
            float acc = 0.0f;
            #pragma unroll
            for (int c = 0; c < 4; ++c) {
                const int j = lane + 64 * c;
                acc = fmaf(HV[rbase + p][j], W4[j], acc);
            }
            #pragma unroll
            for (int off = 32; off > 0; off >>= 1)
                acc += __shfl_down(acc, off, 64);
            if (lane == 0) bout[pbase + p] = acc + bias4;
        }
        return;
    }

    // ---- anti-phase seeding: only the first resident generation delays.
    // Offsets persist through block churn (successor starts when predecessor
    // ends), so pairs stay de-phased for the whole dispatch.
    if ((int)blockIdx.x < 2048) {
        const unsigned n = ((unsigned)blockIdx.x * 2654435761u) >> 27;  // 0..31
        for (unsigned i = 0; i < n; ++i)
            __builtin_amdgcn_s_sleep(13);    // ~832 cyc each; up to ~26k cyc
    }

    // ================= equation path =================
    typedef __bf16 (*HlsT)[MPTS][SKE];
    HlsT Hls = (HlsT)smem;                               // [6][16][260]
    float (*red)[16] = (float (*)[16])smem;              // aliases Hls (guarded)

    const int m    = lane & 15;
    const int q    = lane >> 4;
    const int pb   = blockIdx.x * MPTS;

    f32x4 acc[3][4];                               // [ch][nt], nt = 2c+t
    bf16x8 AH0[4], AL0[4], AH1[4], AL1[4];
    u32x4  BH0[3], BL0[3], BH1[3], BL1[3];

    auto zacc = [&]() {
        #pragma unroll
        for (int ch = 0; ch < 3; ++ch)
            #pragma unroll
            for (int nt = 0; nt < 4; ++nt)
                acc[ch][nt] = (f32x4)0.0f;
    };
    auto loadA = [&](bf16x8 (&AH)[4], bf16x8 (&AL)[4],
                     const __bf16* wh, const __bf16* wl, int ks) {
        #pragma unroll
        for (int nt = 0; nt < 4; ++nt) {
            const int off = (((wv * 4 + nt) * 8 + ks) * 64 + lane) * 8;
            AH[nt] = *(const bf16x8*)(wh + off);
            AL[nt] = *(const bf16x8*)(wl + off);
        }
    };
    // b64 pairs (row base 8B-aligned only -> no b128 fusion); bank-pair map
    // (m + 2q + h) mod 16: all 16 distinct per 16-lane group -> conflict-free.
    auto loadB = [&](u32x4 (&BH)[3], u32x4 (&BL)[3], int ks) {
        const int cb = ks * 32 + q * 8;
        #pragma unroll
        for (int ch = 0; ch < 3; ++ch) {
            const u32x2 h0 = *(const u32x2*)&Hls[ch * 2    ][m][cb];
            const u32x2 h1 = *(const u32x2*)&Hls[ch * 2    ][m][cb + 4];
            const u32x2 l0 = *(const u32x2*)&Hls[ch * 2 + 1][m][cb];
            const u32x2 l1 = *(const u32x2*)&Hls[ch * 2 + 1][m][cb + 4];
            BH[ch] = u32x4{h0[0], h0[1], h1[0], h1[1]};
            BL[ch] = u32x4{l0[0], l0[1], l1[0], l1[1]};
        }
    };
    auto MF = [&](const bf16x8& a, const u32x4& b, const f32x4& c) {
        return __builtin_amdgcn_mfma_f32_16x16x32_bf16(
            a, __builtin_bit_cast(bf16x8, b), c, 0, 0, 0);
    };
    auto mfma36 = [&](const bf16x8 (&AH)[4], const bf16x8 (&AL)[4],
                      const u32x4 (&BH)[3], const u32x4 (&BL)[3]) {
        __builtin_amdgcn_s_setprio(1);
        #pragma unroll
        for (int ch = 0; ch < 3; ++ch)
            #pragma unroll
            for (int nt = 0; nt < 4; ++nt)
                acc[ch][nt] = MF(AH[nt], BH[ch], acc[ch][nt]);
        #pragma unroll
        for (int ch = 0; ch < 3; ++ch)
            #pragma unroll
            for (int nt = 0; nt < 4; ++nt)
                acc[ch][nt] = MF(AH[nt], BL[ch], acc[ch][nt]);
        #pragma unroll
        for (int ch = 0; ch < 3; ++ch)
            #pragma unroll
            for (int nt = 0; nt < 4; ++nt)
                acc[ch][nt] = MF(AL[nt], BH[ch], acc[ch][nt]);
        __builtin_amdgcn_s_setprio(0);
    };

    // ---- layer 0 ----
    {
        const int p  = tid & 15;
        const int cg = (tid >> 4) * 16;
        const int ks = cg >> 5;
        const int t  = (cg >> 4) & 1;
        const float xv = xe[pb + p];
        float vv[16], dd[16], ss[16];
        #pragma unroll
        for (int cc = 0; cc < 16; ++cc) {
            const int c = cg + cc;
            const float w  = W0[c];
            const float bb = b0[c];
            const float v  = fast_tanh(fmaf(xv, w, bb));
            const float s2 = 1.0f - v * v;
            vv[cc] = v;
            dd[cc] = s2 * w;
            ss[cc] = -2.0f * v * s2 * w * w;
        }
        auto packwrite = [&](const float (&a)[16], int cp) {
            #pragma unroll
            for (int g = 0; g < 4; ++g) {
                const packed2 p0 = pack2(a[g * 4 + 0], a[g * 4 + 1]);
                const packed2 p1 = pack2(a[g * 4 + 2], a[g * 4 + 3]);
                u32x2 h, lo;
                h[0]  = p0.hi;  h[1]  = p1.hi;
                lo[0] = p0.lo;  lo[1] = p1.lo;
                const int col = 32 * ks + 8 * g + 4 * t;
                *(u32x2*)&Hls[cp    ][p][col] = h;
                *(u32x2*)&Hls[cp + 1][p][col] = lo;
            }
        };
        packwrite(vv, 0);
        packwrite(dd, 2);
        packwrite(ss, 4);
    }
    __syncthreads();

    // ---- layer 1 GEMM: 8 chunks ----
    zacc();
    loadA(AH0, AL0, Wh, Wl, 0);
    loadB(BH0, BL0, 0);
    #pragma unroll 1
    for (int it = 0; it < 4; ++it) {
        const int ks = it * 2;
        loadA(AH1, AL1, Wh, Wl, ks + 1);
        loadB(BH1, BL1, ks + 1);
        mfma36(AH0, AL0, BH0, BL0);
        if (it < 3) {
            loadA(AH0, AL0, Wh, Wl, ks + 2);
            loadB(BH0, BL0, ks + 2);
        }
        mfma36(AH1, AL1, BH1, BL1);
    }

    // ---- transitions ----
    #pragma unroll 1
    for (int l = 0; l < 2; ++l) {
        const __bf16* whN = Wh + (l + 1) * (HID * HID);
        const __bf16* wlN = Wl + (l + 1) * (HID * HID);
        const float* bl = (l == 0) ? b1 : b2;

        __syncthreads();   // drain: all waves done reading H(l)
        loadA(AH0, AL0, whN, wlN, 2 * wv);
        loadA(AH1, AL1, whN, wlN, 2 * wv + 1);

        u32x4 PH[3][2], PL[3][2];
        #pragma unroll
        for (int c = 0; c < 2; ++c)
            #pragma unroll
            for (int i = 0; i < 4; ++i) {
                const int t  = i >> 1;
                const int r0 = (i & 1) * 2;
                const int nt = c * 2 + t;
                float v2[2], d2[2], s2v[2];
                #pragma unroll
                for (int k = 0; k < 2; ++k) {
                    const int r = r0 + k;
                    const int n = 64 * wv + 32 * c + 16 * t + 4 * q + r;
                    const float zv = acc[0][nt][r] + bl[n];
                    const float zd = acc[1][nt][r];
                    const float zs = acc[2][nt][r];
                    const float v  = fast_tanh(zv);
                    const float s2 = 1.0f - v * v;
                    v2[k]  = v;
                    d2[k]  = s2 * zd;
                    s2v[k] = s2 * zs - 2.0f * v * s2 * zd * zd;
                }
                const packed2 pv = pack2(v2[0],  v2[1]);
                const packed2 pd = pack2(d2[0],  d2[1]);
                const packed2 ps = pack2(s2v[0], s2v[1]);
                PH[0][c][i] = pv.hi;  PL[0][c][i] = pv.lo;
                PH[1][c][i] = pd.hi;  PL[1][c][i] = pd.lo;
                PH[2][c][i] = ps.hi;  PL[2][c][i] = ps.lo;
            }

        // exchange store: b64 pairs (conflict-free map), drains under own MFMAs
        #pragma unroll
        for (int c = 0; c < 2; ++c) {
            const int cb = (2 * wv + c) * 32 + q * 8;
            #pragma unroll
            for (int ch = 0; ch < 3; ++ch) {
                *(u32x2*)&Hls[ch * 2    ][m][cb]     = u32x2{PH[ch][c][0], PH[ch][c][1]};
                *(u32x2*)&Hls[ch * 2    ][m][cb + 4] = u32x2{PH[ch][c][2], PH[ch][c][3]};
                *(u32x2*)&Hls[ch * 2 + 1][m][cb]     = u32x2{PL[ch][c][0], PL[ch][c][1]};
                *(u32x2*)&Hls[ch * 2 + 1][m][cb + 4] = u32x2{PL[ch][c][2], PL[ch][c][3]};
            }
        }

        zacc();
        {
            u32x4 bh[3] = {PH[0][0], PH[1][0], PH[2][0]};
            u32x4 bo[3] = {PL[0][0], PL[1][0], PL[2][0]};
            mfma36(AH0, AL0, bh, bo);
        }
        {
            u32x4 bh[3] = {PH[0][1], PH[1][1], PH[2][1]};
            u32x4 bo[3] = {PL[0][1], PL[1][1], PL[2][1]};
            mfma36(AH1, AL1, bh, bo);
        }

        loadA(AH0, AL0, whN, wlN, (2 * wv + 2) & 7);
        __syncthreads();   // publish H(l+1)
        loadB(BH0, BL0, (2 * wv + 2) & 7);
        #pragma unroll 1
        for (int it = 0; it < 3; ++it) {
            const int kb = (2 * wv + 3 + 2 * it) & 7;
            loadA(AH1, AL1, whN, wlN, kb);
            loadB(BH1, BL1, kb);
            mfma36(AH0, AL0, BH0, BL0);
            if (it < 2) {
                const int kc = (2 * wv + 4 + 2 * it) & 7;
                loadA(AH0, AL0, whN, wlN, kc);
                loadB(BH0, BL0, kc);
            }
            mfma36(AH1, AL1, BH1, BL1);
        }
    }

    // ---- layer 3 finish: s-channel register-direct into W4 dot ----
    {
        float P = 0.0f;
        #pragma unroll
        for (int nt = 0; nt < 4; ++nt)
            #pragma unroll
            for (int r = 0; r < 4; ++r) {
                const int n  = (wv * 4 + nt) * 16 + q * 4 + r;
                const float zv = acc[0][nt][r] + b3[n];
                const float zd = acc[1][nt][r];
                const float zs = acc[2][nt][r];
                const float v  = fast_tanh(zv);
                const float s2 = 1.0f - v * v;
                const float sn = s2 * zs - 2.0f * v * s2 * zd * zd;
                P = fmaf(sn, W4[n], P);
            }
        P += __shfl_xor(P, 16, 64);
        P += __shfl_xor(P, 32, 64);
        __syncthreads();   // all Hls reads done; red may alias Hls
        if (q == 0) red[wv][m] = P;
        __syncthreads();
        if (tid < 16)
            out[pb + tid] = red[0][tid] + red[1][tid] + red[2][tid] + red[3][tid];
    }
}

extern "C" void kernel_launch(void* const* d_in, const int* in_sizes, int n_in,
                              void* d_out, int out_size, void* d_ws, size_t ws_size,
                              hipStream_t stream) {
    const float* xe = (const float*)d_in[0];
    const float* xb = (const float*)d_in[1];
    const float* W0 = (const float*)d_in[2];
    const float* b0 = (const float*)d_in[3];
    const float* W1 = (const float*)d_in[4];
    const float* b1 = (const float*)d_in[5];
    const float* W2 = (const float*)d_in[6];
    const float* b2 = (const float*)d_in[7];
    const float* W3 = (const float*)d_in[8];
    const float* b3 = (const float*)d_in[9];
    const float* W4 = (const float*)d_in[10];
    const float* b4 = (const float*)d_in[11];
    float* out = (float*)d_out;

    const int n_eq = in_sizes[0];   // 262144
    const int n_b  = in_sizes[1];   // 8192

    __bf16* Wh = (__bf16*)d_ws;
    __bf16* Wl = Wh + WELEM;

    const int neqb = n_eq / MPTS;                  // 16384
    const int nbb  = n_b / 16;                     // 512

    prep_w<<<WELEM / 256, 256, 0, stream>>>(W1, W2, W3, Wh, Wl);

    pinn_fused<<<neqb + nbb, 256, 0, stream>>>(
        xe, xb, W0, b0, b1, b2, b3, W4, b4, W1, W2, W3, Wh, Wl, out, neqb, n_eq);
}

// Round 10
// 945.162 us; speedup vs baseline: 1.0183x; 1.0183x over previous
//
#include <hip/hip_runtime.h>

// PoissonPinn, round-13: 3-deep A-prefetch pipeline (L2 queueing tolerance).
//
// R12 post-mortem: b64 LDS fix verified (conflicts 3.78e7->0) but neutral ->
// LDS not critical path. Stagger failed (+outlier) -> removed. Surviving
// model: weight loadA = 46 B/cyc/CU of L2 traffic (~82% of fair share),
// bursty; queueing inflates L2 latency past the 1-chunk prefetch cover ->
// MFMA starves on vmcnt. Fix: 3 A-buffers, chunk k+3 in flight while chunk k
// computes (fully unrolled, static buffer indices).
//
// Kept: truncation pack2 (R11), slot-contiguous b64 LDS SKE=260 (R12),
// own-chunk register-direct mfma36, drain-before-epilogue, fused boundary,
// (256,2).

constexpr int HID   = 256;
constexpr int MPTS  = 16;
constexpr int SKE   = 260;             // row stride elems (520 B, odd x 8B)
constexpr int WELEM = 3 * HID * HID;
constexpr int HLSB  = 6 * MPTS * SKE * 2;   // 49920 B

typedef __bf16 bf16x8 __attribute__((ext_vector_type(8)));
typedef float  f32x4  __attribute__((ext_vector_type(4)));
typedef unsigned int u32x4 __attribute__((ext_vector_type(4)));
typedef unsigned int u32x2 __attribute__((ext_vector_type(2)));

__device__ __forceinline__ float fast_tanh(float x) {
    float e = __expf(2.0f * x);
    return 1.0f - 2.0f / (e + 1.0f);
}

struct packed2 { unsigned hi, lo; };

__device__ __forceinline__ packed2 pack2(float x, float y) {
    const unsigned xb = __float_as_uint(x), yb = __float_as_uint(y);
    const unsigned xh = xb & 0xFFFF0000u, yh = yb & 0xFFFF0000u;
    packed2 r;
    r.hi = (xb >> 16) | yh;
    const float dx = x - __uint_as_float(xh);
    const float dy = y - __uint_as_float(yh);
    r.lo = (__float_as_uint(dx) >> 16) | (__float_as_uint(dy) & 0xFFFF0000u);
    return r;
}

__global__ void prep_w(const float* __restrict__ W1,
                       const float* __restrict__ W2,
                       const float* __restrict__ W3,
                       __bf16* __restrict__ Wh, __bf16* __restrict__ Wl) {
    const int idx = blockIdx.x * 256 + threadIdx.x;
    const int l   = idx >> 16;
    const int r   = idx & 0xFFFF;
    const int NT  = r >> 12;
    const int ks  = (r >> 9) & 7;
    const int ln  = (r >> 3) & 63;
    const int j   = r & 7;
    const int q   = ln >> 4;
    const int mm  = ln & 15;
    const int k   = ks * 32 + ((j >> 2) << 4) + q * 4 + (j & 3);
    const int n   = NT * 16 + mm;
    const float* W = (l == 0) ? W1 : (l == 1) ? W2 : W3;
    const float w  = W[k * HID + n];
    const __bf16 hi = (__bf16)w;
    Wh[idx] = hi;
    Wl[idx] = (__bf16)(w - (float)hi);
}

__global__ __launch_bounds__(256, 2)
void pinn_fused(const float* __restrict__ xe, const float* __restrict__ xb,
                const float* __restrict__ W0, const float* __restrict__ b0,
                const float* __restrict__ b1, const float* __restrict__ b2,
                const float* __restrict__ b3, const float* __restrict__ W4,
                const float* __restrict__ b4,
                const float* __restrict__ W1f, const float* __restrict__ W2f,
                const float* __restrict__ W3f,
                const __bf16* __restrict__ Wh, const __bf16* __restrict__ Wl,
                float* __restrict__ out, int neqb, int n_eq)
{
    __shared__ __align__(16) unsigned char smem[HLSB];

    const int tid  = threadIdx.x;
    const int lane = tid & 63;
    const int wv   = tid >> 6;

    if ((int)blockIdx.x >= neqb) {
        // ================= boundary path =================
        float (*HV)[HID] = (float (*)[HID])smem;
        const int rbase = wv * 4;
        const int pbase = ((int)blockIdx.x - neqb) * 16 + rbase;
        float* bout = out + n_eq;

        #pragma unroll
        for (int c = 0; c < 4; ++c) {
            const int   j  = lane + 64 * c;
            const float w  = W0[j];
            const float bb = b0[j];
            #pragma unroll
            for (int p = 0; p < 4; ++p)
                HV[rbase + p][j] = fast_tanh(xb[pbase + p] * w + bb);
        }
        __syncthreads();

        const float* Ws[3] = {W1f, W2f, W3f};
        const float* bs[3] = {b1, b2, b3};

        #pragma unroll
        for (int l = 0; l < 3; ++l) {
            const float* __restrict__ W = Ws[l];
            const float* __restrict__ b = bs[l];

            float zv[4][4];
            #pragma unroll
            for (int p = 0; p < 4; ++p)
                #pragma unroll
                for (int c = 0; c < 4; ++c)
                    zv[p][c] = b[lane + 64 * c];

            for (int i = 0; i < HID; i += 4) {
                float w[4][4];
                #pragma unroll
                for (int qq = 0; qq < 4; ++qq)
                    #pragma unroll
                    for (int c = 0; c < 4; ++c)
                        w[qq][c] = W[(i + qq) * HID + lane + 64 * c];

                #pragma unroll
                for (int p = 0; p < 4; ++p) {
                    const float4 av = *(const float4*)&HV[rbase + p][i];
                    #pragma unroll
                    for (int qq = 0; qq < 4; ++qq) {
                        const float a_v = ((const float*)&av)[qq];
                        #pragma unroll
                        for (int c = 0; c < 4; ++c)
                            zv[p][c] = fmaf(a_v, w[qq][c], zv[p][c]);
                    }
                }
            }
            __syncthreads();

            #pragma unroll
            for (int p = 0; p < 4; ++p)
                #pragma unroll
                for (int c = 0; c < 4; ++c)
                    HV[rbase + p][lane + 64 * c] = fast_tanh(zv[p][c]);
            __syncthreads();
        }

        const float bias4 = b4[0];
        #pragma unroll
        for (int p = 0; p < 4; ++p) {
            float acc = 0.0f;
            #pragma unroll
            for (int c = 0; c < 4; ++c) {
                const int j = lane + 64 * c;
                acc = fmaf(HV[rbase + p][j], W4[j], acc);
            }
            #pragma unroll
            for (int off = 32; off > 0; off >>= 1)
                acc += __shfl_down(acc, off, 64);
            if (lane == 0) bout[pbase + p] = acc + bias4;
        }
        return;
    }

    // ================= equation path =================
    typedef __bf16 (*HlsT)[MPTS][SKE];
    HlsT Hls = (HlsT)smem;                               // [6][16][260]
    float (*red)[16] = (float (*)[16])smem;              // aliases Hls (guarded)

    const int m    = lane & 15;
    const int q    = lane >> 4;
    const int pb   = blockIdx.x * MPTS;

    f32x4 acc[3][4];                               // [ch][nt], nt = 2c+t
    bf16x8 AH[3][4], AL[3][4];                     // 3-deep A pipeline
    u32x4  BH[2][3], BL[2][3];                     // 2-deep B (LDS)

    auto zacc = [&]() {
        #pragma unroll
        for (int ch = 0; ch < 3; ++ch)
            #pragma unroll
            for (int nt = 0; nt < 4; ++nt)
                acc[ch][nt] = (f32x4)0.0f;
    };
    auto loadA = [&](int ab, const __bf16* wh, const __bf16* wl, int ks) {
        #pragma unroll
        for (int nt = 0; nt < 4; ++nt) {
            const int off = (((wv * 4 + nt) * 8 + ks) * 64 + lane) * 8;
            AH[ab][nt] = *(const bf16x8*)(wh + off);
            AL[ab][nt] = *(const bf16x8*)(wl + off);
        }
    };
    // b64 pairs, conflict-free map (R12, measured 0 conflicts)
    auto loadB = [&](int bb, int ks) {
        const int cb = ks * 32 + q * 8;
        #pragma unroll
        for (int ch = 0; ch < 3; ++ch) {
            const u32x2 h0 = *(const u32x2*)&Hls[ch * 2    ][m][cb];
            const u32x2 h1 = *(const u32x2*)&Hls[ch * 2    ][m][cb + 4];
            const u32x2 l0 = *(const u32x2*)&Hls[ch * 2 + 1][m][cb];
            const u32x2 l1 = *(const u32x2*)&Hls[ch * 2 + 1][m][cb + 4];
            BH[bb][ch] = u32x4{h0[0], h0[1], h1[0], h1[1]};
            BL[bb][ch] = u32x4{l0[0], l0[1], l1[0], l1[1]};
        }
    };
    auto MF = [&](const bf16x8& a, const u32x4& b, const f32x4& c) {
        return __builtin_amdgcn_mfma_f32_16x16x32_bf16(
            a, __builtin_bit_cast(bf16x8, b), c, 0, 0, 0);
    };
    auto mfma36 = [&](int ab, int bb) {
        __builtin_amdgcn_s_setprio(1);
        #pragma unroll
        for (int ch = 0; ch < 3; ++ch)
            #pragma unroll
            for (int nt = 0; nt < 4; ++nt)
                acc[ch][nt] = MF(AH[ab][nt], BH[bb][ch], acc[ch][nt]);
        #pragma unroll
        for (int ch = 0; ch < 3; ++ch)
            #pragma unroll
            for (int nt = 0; nt < 4; ++nt)
                acc[ch][nt] = MF(AH[ab][nt], BL[bb][ch], acc[ch][nt]);
        #pragma unroll
        for (int ch = 0; ch < 3; ++ch)
            #pragma unroll
            for (int nt = 0; nt < 4; ++nt)
                acc[ch][nt] = MF(AL[ab][nt], BH[bb][ch], acc[ch][nt]);
        __builtin_amdgcn_s_setprio(0);
    };
    auto mfma36P = [&](int ab, const u32x4 (&ph)[3], const u32x4 (&pl)[3]) {
        __builtin_amdgcn_s_setprio(1);
        #pragma unroll
        for (int ch = 0; ch < 3; ++ch)
            #pragma unroll
            for (int nt = 0; nt < 4; ++nt)
                acc[ch][nt] = MF(AH[ab][nt], ph[ch], acc[ch][nt]);
        #pragma unroll
        for (int ch = 0; ch < 3; ++ch)
            #pragma unroll
            for (int nt = 0; nt < 4; ++nt)
                acc[ch][nt] = MF(AH[ab][nt], pl[ch], acc[ch][nt]);
        #pragma unroll
        for (int ch = 0; ch < 3; ++ch)
            #pragma unroll
            for (int nt = 0; nt < 4; ++nt)
                acc[ch][nt] = MF(AL[ab][nt], ph[ch], acc[ch][nt]);
        __builtin_amdgcn_s_setprio(0);
    };

    // ---- issue layer-1 chunks 0..2 immediately (hide L2 under layer 0) ----
    loadA(0, Wh, Wl, 0);
    loadA(1, Wh, Wl, 1);
    loadA(2, Wh, Wl, 2);

    // ---- layer 0 ----
    {
        const int p  = tid & 15;
        const int cg = (tid >> 4) * 16;
        const int ks = cg >> 5;
        const int t  = (cg >> 4) & 1;
        const float xv = xe[pb + p];
        float vv[16], dd[16], ss[16];
        #pragma unroll
        for (int cc = 0; cc < 16; ++cc) {
            const int c = cg + cc;
            const float w  = W0[c];
            const float bb = b0[c];
            const float v  = fast_tanh(fmaf(xv, w, bb));
            const float s2 = 1.0f - v * v;
            vv[cc] = v;
            dd[cc] = s2 * w;
            ss[cc] = -2.0f * v * s2 * w * w;
        }
        auto packwrite = [&](const float (&a)[16], int cp) {
            #pragma unroll
            for (int g = 0; g < 4; ++g) {
                const packed2 p0 = pack2(a[g * 4 + 0], a[g * 4 + 1]);
                const packed2 p1 = pack2(a[g * 4 + 2], a[g * 4 + 3]);
                u32x2 h, lo;
                h[0]  = p0.hi;  h[1]  = p1.hi;
                lo[0] = p0.lo;  lo[1] = p1.lo;
                const int col = 32 * ks + 8 * g + 4 * t;
                *(u32x2*)&Hls[cp    ][p][col] = h;
                *(u32x2*)&Hls[cp + 1][p][col] = lo;
            }
        };
        packwrite(vv, 0);
        packwrite(dd, 2);
        packwrite(ss, 4);
    }
    __syncthreads();

    // ---- layer 1 GEMM: 8 chunks, 3-deep A pipeline ----
    zacc();
    loadB(0, 0);
    #pragma unroll
    for (int it = 0; it < 8; ++it) {
        if (it + 1 < 8) loadB((it + 1) & 1, it + 1);
        mfma36(it % 3, it & 1);
        if (it + 3 < 8) loadA(it % 3, Wh, Wl, it + 3);
    }

    // ---- transitions ----
    #pragma unroll 1
    for (int l = 0; l < 2; ++l) {
        const __bf16* whN = Wh + (l + 1) * (HID * HID);
        const __bf16* wlN = Wl + (l + 1) * (HID * HID);
        const float* bl = (l == 0) ? b1 : b2;

        __syncthreads();   // drain: all waves done reading H(l)
        loadA(0, whN, wlN, 2 * wv);               // own chunk c=0
        loadA(1, whN, wlN, 2 * wv + 1);           // own chunk c=1

        u32x4 PH[3][2], PL[3][2];
        #pragma unroll
        for (int c = 0; c < 2; ++c)
            #pragma unroll
            for (int i = 0; i < 4; ++i) {
                const int t  = i >> 1;
                const int r0 = (i & 1) * 2;
                const int nt = c * 2 + t;
                float v2[2], d2[2], s2v[2];
                #pragma unroll
                for (int k = 0; k < 2; ++k) {
                    const int r = r0 + k;
                    const int n = 64 * wv + 32 * c + 16 * t + 4 * q + r;
                    const float zv = acc[0][nt][r] + bl[n];
                    const float zd = acc[1][nt][r];
                    const float zs = acc[2][nt][r];
                    const float v  = fast_tanh(zv);
                    const float s2 = 1.0f - v * v;
                    v2[k]  = v;
                    d2[k]  = s2 * zd;
                    s2v[k] = s2 * zs - 2.0f * v * s2 * zd * zd;
                }
                const packed2 pv = pack2(v2[0],  v2[1]);
                const packed2 pd = pack2(d2[0],  d2[1]);
                const packed2 ps = pack2(s2v[0], s2v[1]);
                PH[0][c][i] = pv.hi;  PL[0][c][i] = pv.lo;
                PH[1][c][i] = pd.hi;  PL[1][c][i] = pd.lo;
                PH[2][c][i] = ps.hi;  PL[2][c][i] = ps.lo;
            }

        // exchange store: b64 pairs (conflict-free), drains under own MFMAs
        #pragma unroll
        for (int c = 0; c < 2; ++c) {
            const int cb = (2 * wv + c) * 32 + q * 8;
            #pragma unroll
            for (int ch = 0; ch < 3; ++ch) {
                *(u32x2*)&Hls[ch * 2    ][m][cb]     = u32x2{PH[ch][c][0], PH[ch][c][1]};
                *(u32x2*)&Hls[ch * 2    ][m][cb + 4] = u32x2{PH[ch][c][2], PH[ch][c][3]};
                *(u32x2*)&Hls[ch * 2 + 1][m][cb]     = u32x2{PL[ch][c][0], PL[ch][c][1]};
                *(u32x2*)&Hls[ch * 2 + 1][m][cb + 4] = u32x2{PL[ch][c][2], PL[ch][c][3]};
            }
        }

        zacc();
        {
            u32x4 ph[3] = {PH[0][0], PH[1][0], PH[2][0]};
            u32x4 pl[3] = {PL[0][0], PL[1][0], PL[2][0]};
            mfma36P(0, ph, pl);
        }
        {
            u32x4 ph[3] = {PH[0][1], PH[1][1], PH[2][1]};
            u32x4 pl[3] = {PL[0][1], PL[1][1], PL[2][1]};
            mfma36P(1, ph, pl);
        }

        loadA(2, whN, wlN, (2 * wv + 2) & 7);     // first LDS chunk
        __syncthreads();   // publish H(l+1)
        loadB(0, (2 * wv + 2) & 7);
        loadA(0, whN, wlN, (2 * wv + 3) & 7);     // 2nd LDS chunk (A0 free)
        loadA(1, whN, wlN, (2 * wv + 4) & 7);     // 3rd LDS chunk
        #pragma unroll
        for (int it = 0; it < 6; ++it) {
            if (it + 1 < 6) loadB((it + 1) & 1, (2 * wv + 3 + it) & 7);
            mfma36((2 + it) % 3, it & 1);
            if (it + 3 < 6) loadA((2 + it) % 3, whN, wlN, (2 * wv + 5 + it) & 7);
        }
    }

    // ---- layer 3 finish: s-channel register-direct into W4 dot ----
    {
        float P = 0.0f;
        #pragma unroll
        for (int nt = 0; nt < 4; ++nt)
            #pragma unroll
            for (int r = 0; r < 4; ++r) {
                const int n  = (wv * 4 + nt) * 16 + q * 4 + r;
                const float zv = acc[0][nt][r] + b3[n];
                const float zd = acc[1][nt][r];
                const float zs = acc[2][nt][r];
                const float v  = fast_tanh(zv);
                const float s2 = 1.0f - v * v;
                const float sn = s2 * zs - 2.0f * v * s2 * zd * zd;
                P = fmaf(sn, W4[n], P);
            }
        P += __shfl_xor(P, 16, 64);
        P += __shfl_xor(P, 32, 64);
        __syncthreads();   // all Hls reads done; red may alias Hls
        if (q == 0) red[wv][m] = P;
        __syncthreads();
        if (tid < 16)
            out[pb + tid] = red[0][tid] + red[1][tid] + red[2][tid] + red[3][tid];
    }
}

extern "C" void kernel_launch(void* const* d_in, const int* in_sizes, int n_in,
                              void* d_out, int out_size, void* d_ws, size_t ws_size,
                              hipStream_t stream) {
    const float* xe = (const float*)d_in[0];
    const float* xb = (const float*)d_in[1];
    const float* W0 = (const float*)d_in[2];
    const float* b0 = (const float*)d_in[3];
    const float* W1 = (const float*)d_in[4];
    const float* b1 = (const float*)d_in[5];
    const float* W2 = (const float*)d_in[6];
    const float* b2 = (const float*)d_in[7];
    const float* W3 = (const float*)d_in[8];
    const float* b3 = (const float*)d_in[9];
    const float* W4 = (const float*)d_in[10];
    const float* b4 = (const float*)d_in[11];
    float* out = (float*)d_out;

    const int n_eq = in_sizes[0];   // 262144
    const int n_b  = in_sizes[1];   // 8192

    __bf16* Wh = (__bf16*)d_ws;
    __bf16* Wl = Wh + WELEM;

    const int neqb = n_eq / MPTS;                  // 16384
    const int nbb  = n_b / 16;                     // 512

    prep_w<<<WELEM / 256, 256, 0, stream>>>(W1, W2, W3, Wh, Wl);

    pinn_fused<<<neqb + nbb, 256, 0, stream>>>(
        xe, xb, W0, b0, b1, b2, b3, W4, b4, W1, W2, W3, Wh, Wl, out, neqb, n_eq);
}

// Round 11
// 739.754 us; speedup vs baseline: 1.3010x; 1.2777x over previous
//
#include <hip/hip_runtime.h>

// PoissonPinn, round-14: per-channel precision — v keeps 3-term hi/lo split,
// d and s drop to single-term bf16 (RNE-rounded storage).
//
// R13 post-mortem: 3-deep prefetch neutral -> load latency NOT the stall.
// Falsified so far: scheduling, L2 BW, bank conflicts, load latency. Surviving
// model: MFMA pipe work (448us) + VALU/barrier residual, phase-locked and
// additive. This round shrinks the MFMA term: 36 -> 20 MFMA/chunk
// (v:3 terms, d:1, s:1), floor 448 -> 249us. Error budget: d/s single-term
// ~2^-10 rel/layer + RNE rep 2^-9; forward estimate absmax 1-4e-4 < 8.5e-4.
//
// Kept from R13: 3-deep A pipeline, slot-contiguous b64 LDS (SKE=260,
// conflicts measured 0), own-chunk register-direct MFMAs, truncation pack2
// for v, fused boundary, (256,2). LDS planes 6->4 (33 KB).

constexpr int HID   = 256;
constexpr int MPTS  = 16;
constexpr int SKE   = 260;             // row stride elems (520 B, odd x 8B)
constexpr int WELEM = 3 * HID * HID;
constexpr int HLSB  = 4 * MPTS * SKE * 2;   // 33280 B

typedef __bf16 bf16x8 __attribute__((ext_vector_type(8)));
typedef float  f32x4  __attribute__((ext_vector_type(4)));
typedef unsigned int u32x4 __attribute__((ext_vector_type(4)));
typedef unsigned int u32x2 __attribute__((ext_vector_type(2)));

__device__ __forceinline__ float fast_tanh(float x) {
    float e = __expf(2.0f * x);
    return 1.0f - 2.0f / (e + 1.0f);
}

struct packed2 { unsigned hi, lo; };

// truncation split pack (v channel: hi+lo, error ~2^-20 after 3-term MFMA)
__device__ __forceinline__ packed2 pack2(float x, float y) {
    const unsigned xb = __float_as_uint(x), yb = __float_as_uint(y);
    const unsigned xh = xb & 0xFFFF0000u, yh = yb & 0xFFFF0000u;
    packed2 r;
    r.hi = (xb >> 16) | yh;
    const float dx = x - __uint_as_float(xh);
    const float dy = y - __uint_as_float(yh);
    r.lo = (__float_as_uint(dx) >> 16) | (__float_as_uint(dy) & 0xFFFF0000u);
    return r;
}

// RNE bf16 pair pack (d/s channels: single plane, rep error 2^-9)
__device__ __forceinline__ unsigned rnepack(float x, float y) {
    unsigned xb = __float_as_uint(x), yb = __float_as_uint(y);
    xb += 0x7FFFu + ((xb >> 16) & 1u);
    yb += 0x7FFFu + ((yb >> 16) & 1u);
    return (xb >> 16) | (yb & 0xFFFF0000u);
}

__global__ void prep_w(const float* __restrict__ W1,
                       const float* __restrict__ W2,
                       const float* __restrict__ W3,
                       __bf16* __restrict__ Wh, __bf16* __restrict__ Wl) {
    const int idx = blockIdx.x * 256 + threadIdx.x;
    const int l   = idx >> 16;
    const int r   = idx & 0xFFFF;
    const int NT  = r >> 12;
    const int ks  = (r >> 9) & 7;
    const int ln  = (r >> 3) & 63;
    const int j   = r & 7;
    const int q   = ln >> 4;
    const int mm  = ln & 15;
    const int k   = ks * 32 + ((j >> 2) << 4) + q * 4 + (j & 3);
    const int n   = NT * 16 + mm;
    const float* W = (l == 0) ? W1 : (l == 1) ? W2 : W3;
    const float w  = W[k * HID + n];
    const __bf16 hi = (__bf16)w;
    Wh[idx] = hi;
    Wl[idx] = (__bf16)(w - (float)hi);
}

__global__ __launch_bounds__(256, 2)
void pinn_fused(const float* __restrict__ xe, const float* __restrict__ xb,
                const float* __restrict__ W0, const float* __restrict__ b0,
                const float* __restrict__ b1, const float* __restrict__ b2,
                const float* __restrict__ b3, const float* __restrict__ W4,
                const float* __restrict__ b4,
                const float* __restrict__ W1f, const float* __restrict__ W2f,
                const float* __restrict__ W3f,
                const __bf16* __restrict__ Wh, const __bf16* __restrict__ Wl,
                float* __restrict__ out, int neqb, int n_eq)
{
    __shared__ __align__(16) unsigned char smem[HLSB];

    const int tid  = threadIdx.x;
    const int lane = tid & 63;
    const int wv   = tid >> 6;

    if ((int)blockIdx.x >= neqb) {
        // ================= boundary path =================
        float (*HV)[HID] = (float (*)[HID])smem;     // 16 KB < 33 KB
        const int rbase = wv * 4;
        const int pbase = ((int)blockIdx.x - neqb) * 16 + rbase;
        float* bout = out + n_eq;

        #pragma unroll
        for (int c = 0; c < 4; ++c) {
            const int   j  = lane + 64 * c;
            const float w  = W0[j];
            const float bb = b0[j];
            #pragma unroll
            for (int p = 0; p < 4; ++p)
                HV[rbase + p][j] = fast_tanh(xb[pbase + p] * w + bb);
        }
        __syncthreads();

        const float* Ws[3] = {W1f, W2f, W3f};
        const float* bs[3] = {b1, b2, b3};

        #pragma unroll
        for (int l = 0; l < 3; ++l) {
            const float* __restrict__ W = Ws[l];
            const float* __restrict__ b = bs[l];

            float zv[4][4];
            #pragma unroll
            for (int p = 0; p < 4; ++p)
                #pragma unroll
                for (int c = 0; c < 4; ++c)
                    zv[p][c] = b[lane + 64 * c];

            for (int i = 0; i < HID; i += 4) {
                float w[4][4];
                #pragma unroll
                for (int qq = 0; qq < 4; ++qq)
                    #pragma unroll
                    for (int c = 0; c < 4; ++c)
                        w[qq][c] = W[(i + qq) * HID + lane + 64 * c];

                #pragma unroll
                for (int p = 0; p < 4; ++p) {
                    const float4 av = *(const float4*)&HV[rbase + p][i];
                    #pragma unroll
                    for (int qq = 0; qq < 4; ++qq) {
                        const float a_v = ((const float*)&av)[qq];
                        #pragma unroll
                        for (int c = 0; c < 4; ++c)
                            zv[p][c] = fmaf(a_v, w[qq][c], zv[p][c]);
                    }
                }
            }
            __syncthreads();

            #pragma unroll
            for (int p = 0; p < 4; ++p)
                #pragma unroll
                for (int c = 0; c < 4; ++c)
                    HV[rbase + p][lane + 64 * c] = fast_tanh(zv[p][c]);
            __syncthreads();
        }

        const float bias4 = b4[0];
        #pragma unroll
        for (int p = 0; p < 4; ++p) {
            float acc = 0.0f;
            #pragma unroll
            for (int c = 0; c < 4; ++c) {
                const int j = lane + 64 * c;
                acc = fmaf(HV[rbase + p][j], W4[j], acc);
            }
            #pragma unroll
            for (int off = 32; off > 0; off >>= 1)
                acc += __shfl_down(acc, off, 64);
            if (lane == 0) bout[pbase + p] = acc + bias4;
        }
        return;
    }

    // ================= equation path =================
    // LDS planes: 0 = v-hi, 1 = v-lo, 2 = d (RNE bf16), 3 = s (RNE bf16)
    typedef __bf16 (*HlsT)[MPTS][SKE];
    HlsT Hls = (HlsT)smem;                               // [4][16][260]
    float (*red)[16] = (float (*)[16])smem;              // aliases Hls (guarded)

    const int m    = lane & 15;
    const int q    = lane >> 4;
    const int pb   = blockIdx.x * MPTS;

    f32x4 acc[3][4];                               // [ch][nt], nt = 2c+t
    bf16x8 AH[3][4], AL[3][4];                     // 3-deep A pipeline
    u32x4  B[2][4];                                // 2-deep B: [buf][plane]

    auto zacc = [&]() {
        #pragma unroll
        for (int ch = 0; ch < 3; ++ch)
            #pragma unroll
            for (int nt = 0; nt < 4; ++nt)
                acc[ch][nt] = (f32x4)0.0f;
    };
    auto loadA = [&](int ab, const __bf16* wh, const __bf16* wl, int ks) {
        #pragma unroll
        for (int nt = 0; nt < 4; ++nt) {
            const int off = (((wv * 4 + nt) * 8 + ks) * 64 + lane) * 8;
            AH[ab][nt] = *(const bf16x8*)(wh + off);
            AL[ab][nt] = *(const bf16x8*)(wl + off);
        }
    };
    // b64 pairs, conflict-free map (R12/R13, measured 0 conflicts)
    auto loadB = [&](int bb, int ks) {
        const int cb = ks * 32 + q * 8;
        #pragma unroll
        for (int pl = 0; pl < 4; ++pl) {
            const u32x2 a = *(const u32x2*)&Hls[pl][m][cb];
            const u32x2 b2 = *(const u32x2*)&Hls[pl][m][cb + 4];
            B[bb][pl] = u32x4{a[0], a[1], b2[0], b2[1]};
        }
    };
    auto MF = [&](const bf16x8& a, const u32x4& b, const f32x4& c) {
        return __builtin_amdgcn_mfma_f32_16x16x32_bf16(
            a, __builtin_bit_cast(bf16x8, b), c, 0, 0, 0);
    };
    // 20 MFMAs/chunk: v = AhVh + AhVl + AlVh (12), d = AhDh (4), s = AhSh (4)
    auto mfma20 = [&](int ab, int bb) {
        __builtin_amdgcn_s_setprio(1);
        #pragma unroll
        for (int nt = 0; nt < 4; ++nt) acc[0][nt] = MF(AH[ab][nt], B[bb][0], acc[0][nt]);
        #pragma unroll
        for (int nt = 0; nt < 4; ++nt) acc[1][nt] = MF(AH[ab][nt], B[bb][2], acc[1][nt]);
        #pragma unroll
        for (int nt = 0; nt < 4; ++nt) acc[2][nt] = MF(AH[ab][nt], B[bb][3], acc[2][nt]);
        #pragma unroll
        for (int nt = 0; nt < 4; ++nt) acc[0][nt] = MF(AH[ab][nt], B[bb][1], acc[0][nt]);
        #pragma unroll
        for (int nt = 0; nt < 4; ++nt) acc[0][nt] = MF(AL[ab][nt], B[bb][0], acc[0][nt]);
        __builtin_amdgcn_s_setprio(0);
    };
    auto mfma20P = [&](int ab, const u32x4& vh, const u32x4& vl,
                       const u32x4& dh, const u32x4& sh) {
        __builtin_amdgcn_s_setprio(1);
        #pragma unroll
        for (int nt = 0; nt < 4; ++nt) acc[0][nt] = MF(AH[ab][nt], vh, acc[0][nt]);
        #pragma unroll
        for (int nt = 0; nt < 4; ++nt) acc[1][nt] = MF(AH[ab][nt], dh, acc[1][nt]);
        #pragma unroll
        for (int nt = 0; nt < 4; ++nt) acc[2][nt] = MF(AH[ab][nt], sh, acc[2][nt]);
        #pragma unroll
        for (int nt = 0; nt < 4; ++nt) acc[0][nt] = MF(AH[ab][nt], vl, acc[0][nt]);
        #pragma unroll
        for (int nt = 0; nt < 4; ++nt) acc[0][nt] = MF(AL[ab][nt], vh, acc[0][nt]);
        __builtin_amdgcn_s_setprio(0);
    };

    // ---- issue layer-1 chunks 0..2 (L2 latency hides under layer 0) ----
    loadA(0, Wh, Wl, 0);
    loadA(1, Wh, Wl, 1);
    loadA(2, Wh, Wl, 2);

    // ---- layer 0 ----
    {
        const int p  = tid & 15;
        const int cg = (tid >> 4) * 16;
        const int ks = cg >> 5;
        const int t  = (cg >> 4) & 1;
        const float xv = xe[pb + p];
        float vv[16], dd[16], ss[16];
        #pragma unroll
        for (int cc = 0; cc < 16; ++cc) {
            const int c = cg + cc;
            const float w  = W0[c];
            const float bb = b0[c];
            const float v  = fast_tanh(fmaf(xv, w, bb));
            const float s2 = 1.0f - v * v;
            vv[cc] = v;
            dd[cc] = s2 * w;
            ss[cc] = -2.0f * v * s2 * w * w;
        }
        #pragma unroll
        for (int g = 0; g < 4; ++g) {
            const int col = 32 * ks + 8 * g + 4 * t;
            const packed2 p0 = pack2(vv[g * 4 + 0], vv[g * 4 + 1]);
            const packed2 p1 = pack2(vv[g * 4 + 2], vv[g * 4 + 3]);
            u32x2 h, lo;
            h[0]  = p0.hi;  h[1]  = p1.hi;
            lo[0] = p0.lo;  lo[1] = p1.lo;
            *(u32x2*)&Hls[0][p][col] = h;
            *(u32x2*)&Hls[1][p][col] = lo;
            u32x2 dpk, spk;
            dpk[0] = rnepack(dd[g * 4 + 0], dd[g * 4 + 1]);
            dpk[1] = rnepack(dd[g * 4 + 2], dd[g * 4 + 3]);
            spk[0] = rnepack(ss[g * 4 + 0], ss[g * 4 + 1]);
            spk[1] = rnepack(ss[g * 4 + 2], ss[g * 4 + 3]);
            *(u32x2*)&Hls[2][p][col] = dpk;
            *(u32x2*)&Hls[3][p][col] = spk;
        }
    }
    __syncthreads();

    // ---- layer 1 GEMM: 8 chunks, 3-deep A pipeline ----
    zacc();
    loadB(0, 0);
    #pragma unroll
    for (int it = 0; it < 8; ++it) {
        if (it + 1 < 8) loadB((it + 1) & 1, it + 1);
        mfma20(it % 3, it & 1);
        if (it + 3 < 8) loadA(it % 3, Wh, Wl, it + 3);
    }

    // ---- transitions ----
    #pragma unroll 1
    for (int l = 0; l < 2; ++l) {
        const __bf16* whN = Wh + (l + 1) * (HID * HID);
        const __bf16* wlN = Wl + (l + 1) * (HID * HID);
        const float* bl = (l == 0) ? b1 : b2;

        __syncthreads();   // drain: all waves done reading H(l)
        loadA(0, whN, wlN, 2 * wv);               // own chunk c=0
        loadA(1, whN, wlN, 2 * wv + 1);           // own chunk c=1

        u32x4 PVH[2], PVL[2], PD[2], PS[2];
        #pragma unroll
        for (int c = 0; c < 2; ++c)
            #pragma unroll
            for (int i = 0; i < 4; ++i) {
                const int t  = i >> 1;
                const int r0 = (i & 1) * 2;
                const int nt = c * 2 + t;
                float v2[2], d2[2], s2v[2];
                #pragma unroll
                for (int k = 0; k < 2; ++k) {
                    const int r = r0 + k;
                    const int n = 64 * wv + 32 * c + 16 * t + 4 * q + r;
                    const float zv = acc[0][nt][r] + bl[n];
                    const float zd = acc[1][nt][r];
                    const float zs = acc[2][nt][r];
                    const float v  = fast_tanh(zv);
                    const float s2 = 1.0f - v * v;
                    v2[k]  = v;
                    d2[k]  = s2 * zd;
                    s2v[k] = s2 * zs - 2.0f * v * s2 * zd * zd;
                }
                const packed2 pv = pack2(v2[0], v2[1]);
                PVH[c][i] = pv.hi;
                PVL[c][i] = pv.lo;
                PD[c][i]  = rnepack(d2[0],  d2[1]);
                PS[c][i]  = rnepack(s2v[0], s2v[1]);
            }

        // exchange store: 16 b64 writes (conflict-free), drain under own MFMAs
        #pragma unroll
        for (int c = 0; c < 2; ++c) {
            const int cb = (2 * wv + c) * 32 + q * 8;
            *(u32x2*)&Hls[0][m][cb]     = u32x2{PVH[c][0], PVH[c][1]};
            *(u32x2*)&Hls[0][m][cb + 4] = u32x2{PVH[c][2], PVH[c][3]};
            *(u32x2*)&Hls[1][m][cb]     = u32x2{PVL[c][0], PVL[c][1]};
            *(u32x2*)&Hls[1][m][cb + 4] = u32x2{PVL[c][2], PVL[c][3]};
            *(u32x2*)&Hls[2][m][cb]     = u32x2{PD[c][0], PD[c][1]};
            *(u32x2*)&Hls[2][m][cb + 4] = u32x2{PD[c][2], PD[c][3]};
            *(u32x2*)&Hls[3][m][cb]     = u32x2{PS[c][0], PS[c][1]};
            *(u32x2*)&Hls[3][m][cb + 4] = u32x2{PS[c][2], PS[c][3]};
        }

        zacc();
        mfma20P(0, PVH[0], PVL[0], PD[0], PS[0]);
        mfma20P(1, PVH[1], PVL[1], PD[1], PS[1]);

        loadA(2, whN, wlN, (2 * wv + 2) & 7);     // first LDS chunk
        __syncthreads();   // publish H(l+1)
        loadB(0, (2 * wv + 2) & 7);
        loadA(0, whN, wlN, (2 * wv + 3) & 7);
        loadA(1, whN, wlN, (2 * wv + 4) & 7);
        #pragma unroll
        for (int it = 0; it < 6; ++it) {
            if (it + 1 < 6) loadB((it + 1) & 1, (2 * wv + 3 + it) & 7);
            mfma20((2 + it) % 3, it & 1);
            if (it + 3 < 6) loadA((2 + it) % 3, whN, wlN, (2 * wv + 5 + it) & 7);
        }
    }

    // ---- layer 3 finish: s-channel register-direct into W4 dot ----
    {
        float P = 0.0f;
        #pragma unroll
        for (int nt = 0; nt < 4; ++nt)
            #pragma unroll
            for (int r = 0; r < 4; ++r) {
                const int n  = (wv * 4 + nt) * 16 + q * 4 + r;
                const float zv = acc[0][nt][r] + b3[n];
                const float zd = acc[1][nt][r];
                const float zs = acc[2][nt][r];
                const float v  = fast_tanh(zv);
                const float s2 = 1.0f - v * v;
                const float sn = s2 * zs - 2.0f * v * s2 * zd * zd;
                P = fmaf(sn, W4[n], P);
            }
        P += __shfl_xor(P, 16, 64);
        P += __shfl_xor(P, 32, 64);
        __syncthreads();   // all Hls reads done; red may alias Hls
        if (q == 0) red[wv][m] = P;
        __syncthreads();
        if (tid < 16)
            out[pb + tid] = red[0][tid] + red[1][tid] + red[2][tid] + red[3][tid];
    }
}

extern "C" void kernel_launch(void* const* d_in, const int* in_sizes, int n_in,
                              void* d_out, int out_size, void* d_ws, size_t ws_size,
                              hipStream_t stream) {
    const float* xe = (const float*)d_in[0];
    const float* xb = (const float*)d_in[1];
    const float* W0 = (const float*)d_in[2];
    const float* b0 = (const float*)d_in[3];
    const float* W1 = (const float*)d_in[4];
    const float* b1 = (const float*)d_in[5];
    const float* W2 = (const float*)d_in[6];
    const float* b2 = (const float*)d_in[7];
    const float* W3 = (const float*)d_in[8];
    const float* b3 = (const float*)d_in[9];
    const float* W4 = (const float*)d_in[10];
    const float* b4 = (const float*)d_in[11];
    float* out = (float*)d_out;

    const int n_eq = in_sizes[0];   // 262144
    const int n_b  = in_sizes[1];   // 8192

    __bf16* Wh = (__bf16*)d_ws;
    __bf16* Wl = Wh + WELEM;

    const int neqb = n_eq / MPTS;                  // 16384
    const int nbb  = n_b / 16;                     // 512

    prep_w<<<WELEM / 256, 256, 0, stream>>>(W1, W2, W3, Wh, Wl);

    pinn_fused<<<neqb + nbb, 256, 0, stream>>>(
        xe, xb, W0, b0, b1, b2, b3, W4, b4, W1, W2, W3, Wh, Wl, out, neqb, n_eq);
}